// Round 10
// baseline (960.826 us; speedup 1.0000x reference)
//
#include <hip/hip_runtime.h>
#include <hip/hip_bf16.h>
#include <stdint.h>

#define B 4
#define S 2048
#define D 1024
#define H 16
#define DH 64
#define M_TOT (B*S)
#define BH (B*H)

typedef unsigned short u16;
typedef unsigned int u32;
typedef __attribute__((ext_vector_type(4))) float f32x4;
typedef __attribute__((ext_vector_type(16))) float f32x16;
typedef __attribute__((ext_vector_type(8))) short bf16x8;
typedef __attribute__((ext_vector_type(2))) unsigned int u32x2;

typedef const __attribute__((address_space(1))) unsigned int* gp_t;
typedef __attribute__((address_space(3))) unsigned int* lp_t;

__device__ __forceinline__ void gload_lds16(const void* g, void* l) {
    __builtin_amdgcn_global_load_lds((gp_t)g, (lp_t)l, 16, 0, 0);
}

__device__ __forceinline__ float bf2f(u16 u) {
    u32 t = ((u32)u) << 16;
    float f; __builtin_memcpy(&f, &t, 4); return f;
}
__device__ __forceinline__ u16 f2bf(float f) {   // RTNE
    u32 u; __builtin_memcpy(&u, &f, 4);
    u += 0x7fffu + ((u >> 16) & 1u);
    return (u16)(u >> 16);
}
__device__ __forceinline__ u32 packbf(float lo, float hi_) {
    __hip_bfloat162 h = __float22bfloat162_rn(float2{lo, hi_});
    u32 r; __builtin_memcpy(&r, &h, 4); return r;
}

__device__ __forceinline__ float exp2_fast(float x) { return __builtin_amdgcn_exp2f(x); }

#if __has_builtin(__builtin_amdgcn_permlane32_swap)
__device__ __forceinline__ void plswap(u32& a, u32& bb) {
    u32x2 r = __builtin_amdgcn_permlane32_swap(a, bb, false, false);
    a = r.x; bb = r.y;
}
#else
__device__ __forceinline__ void plswap(u32& a, u32& bb) {
    int hi = (threadIdx.x >> 5) & 1;
    u32 ra = (u32)__shfl_xor((int)a, 32);
    u32 rb = (u32)__shfl_xor((int)bb, 32);
    u32 na = hi ? rb : a;
    u32 nb = hi ? bb : ra;
    a = na; bb = nb;
}
#endif

// ---------------- fused fp32 -> bf16 cast for x + 4 weights ----------------
__global__ __launch_bounds__(256)
void cvt_all_kernel(const float* __restrict__ x,
                    const float* __restrict__ wq, const float* __restrict__ wk,
                    const float* __restrict__ wv, const float* __restrict__ wo,
                    u16* __restrict__ xb, u16* __restrict__ wqb, u16* __restrict__ wkb,
                    u16* __restrict__ wvb, u16* __restrict__ wob)
{
    const size_t MD = (size_t)M_TOT * D;
    const size_t WD = (size_t)D * D;       // 2^20
    size_t i = ((size_t)blockIdx.x * 256 + threadIdx.x) * 8;
    const float* src; u16* dst; size_t off;
    if (i < MD) { src = x; dst = xb; off = i; }
    else {
        size_t j = i - MD;
        int wsel = (int)(j >> 20);
        off = j & (WD - 1);
        if      (wsel == 0) { src = wq; dst = wqb; }
        else if (wsel == 1) { src = wk; dst = wkb; }
        else if (wsel == 2) { src = wv; dst = wvb; }
        else                { src = wo; dst = wob; }
    }
    float4 a = *(const float4*)(src + off);
    float4 b = *(const float4*)(src + off + 4);
    union { u16 u[8]; bf16x8 v; } o;
    o.u[0] = f2bf(a.x); o.u[1] = f2bf(a.y); o.u[2] = f2bf(a.z); o.u[3] = f2bf(a.w);
    o.u[4] = f2bf(b.x); o.u[5] = f2bf(b.y); o.u[6] = f2bf(b.z); o.u[7] = f2bf(b.w);
    *(bf16x8*)(dst + off) = o.v;
}

// ---------------- bf16 MFMA GEMM (m97 structure) ----------------
// QKV mode (DO_ROPE=1): z=0 -> Q rope + cs2 scale; z=1 -> K rope;
// z=2 -> V written TRANSPOSED into Vt[(b*16+h)*64+dh][s] (vtrans fused).
template<int WRITE_BF16, int DO_ROPE>
__global__ __launch_bounds__(256)
void gemm_mfma(const u16* __restrict__ X,
               const u16* __restrict__ W0, const u16* __restrict__ W1, const u16* __restrict__ W2,
               void* Y0, void* Y1, void* Y2,
               const float* __restrict__ cosT, const float* __restrict__ sinT)
{
    __shared__ __align__(16) u16 Al[128 * 32];
    __shared__ __align__(16) u16 Bl[128 * 32];

    const u16* Wm = (blockIdx.z == 0) ? W0 : (blockIdx.z == 1) ? W1 : W2;
    void* Yv      = (blockIdx.z == 0) ? Y0 : (blockIdx.z == 1) ? Y1 : Y2;

    const int t = threadIdx.x;
    const int w = t >> 6, ll = t & 63;
    const int wr = w >> 1, wc = w & 1;
    const int g = ll >> 4, lc = ll & 15;
    const int m0 = blockIdx.x * 128, n0 = blockIdx.y * 128;

    const int srow = t >> 2;
    const int scol = (t & 3) * 8;

    const u16* Xa = X + (size_t)m0 * D;
    const u16* Wa = Wm + (size_t)n0 * D;

    f32x4 acc[4][4];
    #pragma unroll
    for (int i = 0; i < 4; ++i)
        #pragma unroll
        for (int j = 0; j < 4; ++j)
            acc[i][j] = (f32x4){0.f, 0.f, 0.f, 0.f};

    for (int k0 = 0; k0 < D; k0 += 32) {
        gload_lds16(Xa + (size_t)(srow)      * D + k0 + scol, &Al[(w * 64) * 8]);
        gload_lds16(Xa + (size_t)(64 + srow) * D + k0 + scol, &Al[(256 + w * 64) * 8]);
        gload_lds16(Wa + (size_t)(srow)      * D + k0 + scol, &Bl[(w * 64) * 8]);
        gload_lds16(Wa + (size_t)(64 + srow) * D + k0 + scol, &Bl[(256 + w * 64) * 8]);
        __syncthreads();

        bf16x8 af[4], bf[4];
        #pragma unroll
        for (int i = 0; i < 4; ++i)
            af[i] = *(const bf16x8*)&Al[(wr * 64 + i * 16 + lc) * 32 + g * 8];
        #pragma unroll
        for (int j = 0; j < 4; ++j)
            bf[j] = *(const bf16x8*)&Bl[(wc * 64 + j * 16 + lc) * 32 + g * 8];

        #pragma unroll
        for (int i = 0; i < 4; ++i)
            #pragma unroll
            for (int j = 0; j < 4; ++j)
                acc[i][j] = __builtin_amdgcn_mfma_f32_16x16x32_bf16(af[i], bf[j], acc[i][j], 0, 0, 0);
        __syncthreads();
    }

    if (DO_ROPE && blockIdx.z < 2) {
        const float scale = (blockIdx.z == 0) ? (0.125f * 1.44269504f) : 1.0f;
        u16* Y = (u16*)Yv;
        #pragma unroll
        for (int i = 0; i < 4; ++i)
            #pragma unroll
            for (int r = 0; r < 4; ++r) {
                int row = m0 + wr * 64 + i * 16 + g * 4 + r;
                int s = row & (S - 1);
                #pragma unroll
                for (int jh = 0; jh < 2; ++jh) {
                    float c  = cosT[s * DH + jh * 16 + lc];
                    float sn = sinT[s * DH + jh * 16 + lc];
                    float a0 = acc[i][jh][r], a1 = acc[i][jh + 2][r];
                    size_t base = (size_t)row * D + n0 + wc * 64;
                    Y[base + jh * 16 + lc]       = f2bf((a0 * c - a1 * sn) * scale);
                    Y[base + (jh + 2) * 16 + lc] = f2bf((a1 * c + a0 * sn) * scale);
                }
            }
    } else if (DO_ROPE) {
        // z==2: V projection, write transposed: Vt[(b*16 + col/64)*64 + col%64][s]
        u16* Y = (u16*)Yv;
        #pragma unroll
        for (int i = 0; i < 4; ++i)
            #pragma unroll
            for (int j = 0; j < 4; ++j) {
                int row = m0 + wr * 64 + i * 16 + g * 4;       // token index (r=0)
                int col = n0 + wc * 64 + j * 16 + lc;          // feature index
                int bt = row >> 11, s = row & (S - 1);
                size_t vtrow = (size_t)(bt * 16 + (col >> 6)) * 64 + (col & 63);
                u32 w0 = packbf(acc[i][j][0], acc[i][j][1]);
                u32 w1 = packbf(acc[i][j][2], acc[i][j][3]);
                u32x2 pr; pr.x = w0; pr.y = w1;
                *(u32x2*)&Y[vtrow * S + s] = pr;               // 4 consecutive s, 8B store
            }
    } else if (WRITE_BF16) {
        u16* Y = (u16*)Yv;
        #pragma unroll
        for (int i = 0; i < 4; ++i)
            #pragma unroll
            for (int j = 0; j < 4; ++j)
                #pragma unroll
                for (int r = 0; r < 4; ++r) {
                    int row = m0 + wr * 64 + i * 16 + g * 4 + r;
                    int col = n0 + wc * 64 + j * 16 + lc;
                    Y[(size_t)row * D + col] = f2bf(acc[i][j][r]);
                }
    } else {
        float* Y = (float*)Yv;
        #pragma unroll
        for (int i = 0; i < 4; ++i)
            #pragma unroll
            for (int j = 0; j < 4; ++j)
                #pragma unroll
                for (int r = 0; r < 4; ++r) {
                    int row = m0 + wr * 64 + i * 16 + g * 4 + r;
                    int col = n0 + wc * 64 + j * 16 + lc;
                    Y[(size_t)row * D + col] = acc[i][j][r];
                }
    }
}

// ---------------- MFMA flash attention: key-split 8-wave blocks ------------
// 512 threads = 8 waves: wq4 = w&3 picks the 64-q-row group, kh = w>>2 picks
// the key half of each staged 128-key tile (waves 0-3: keys 0-63, waves 4-7:
// keys 64-127). No-max softmax => partials combine by pure ADD at the end.
// 4 waves/SIMD occupancy; one shared staging stream, 64KB dbuf LDS.
#define QBLK 256
#define KVT 128
#define NT (S / KVT)

__global__ __launch_bounds__(512, 4)
void attn_mfma(const u16* __restrict__ Q, const u16* __restrict__ Kg,
               const u16* __restrict__ Vt, u16* __restrict__ CTX)
{
    __shared__ __align__(16) u16 smem[32768];   // 2 x (K 16KB + V 16KB)

    const int t   = threadIdx.x;
    const int w   = t >> 6;          // 0..7
    const int wq4 = w & 3;           // q-wave
    const int kh  = w >> 2;          // key-half
    const int ll  = t & 63;
    const int q   = t & 31;
    const int hi  = (t >> 5) & 1;

    // XCD-chunked swizzle: 8 bh per XCD
    const int bid  = blockIdx.x;          // 0..511
    const int xcd  = bid & 7;
    const int slot = bid >> 3;            // 0..63
    const int bh   = xcd * 8 + (slot >> 3);
    const int qb   = slot & 7;
    const int b = bh >> 4, h = bh & 15;
    const int q0 = qb * QBLK;
    const int qbase = q0 + wq4 * 64;

    // Q as B-fragments for 2 q-groups (same for both key-halves)
    bf16x8 qf[2][4];
    #pragma unroll
    for (int qg = 0; qg < 2; ++qg) {
        const u16* qp = &Q[(size_t)(b*S + qbase + qg*32 + q) * D + h*DH + hi*8];
        qf[qg][0] = *(const bf16x8*)(qp);
        qf[qg][1] = *(const bf16x8*)(qp + 16);
        qf[qg][2] = *(const bf16x8*)(qp + 32);
        qf[qg][3] = *(const bf16x8*)(qp + 48);
    }

    bf16x8 ones;
    {
        union { u16 u[8]; bf16x8 v; } ou;
        #pragma unroll
        for (int i = 0; i < 8; ++i) ou.u[i] = 0x3f80;   // bf16 1.0
        ones = ou.v;
    }

    f32x16 po[4], lsum[2], zv;
    #pragma unroll
    for (int i = 0; i < 16; ++i) {
        po[0][i] = 0.f; po[1][i] = 0.f; po[2][i] = 0.f; po[3][i] = 0.f;
        lsum[0][i] = 0.f; lsum[1][i] = 0.f; zv[i] = 0.f;
    }

    // K staging (128B rows, 8 lanes/row): 512 thr x 16B = 64 rows/issue
    const int ksrow = t >> 3;                                 // 0..63
    const int kscol = (((t & 7) << 4) ^ ((ksrow & 7) << 4)) >> 1;
    // V staging (256B rows, 16 lanes/row): 32 rows/issue
    const int vsrow = t >> 4;                                 // 0..31
    const int vscol = (((t & 15) ^ (vsrow & 15)) << 3);       // u16 units
    const int rsw  = (q & 7) << 4;    // K read swizzle (bytes)
    const int vsw  = (q & 15) << 4;   // V read swizzle (bytes)

    u16* buf0 = smem;
    u16* buf1 = smem + 16384;

    const u16* kg = Kg + ((size_t)(b * S) + ksrow) * D + (size_t)h * DH + kscol;
    const u16* vg = Vt + ((size_t)bh * DH + vsrow) * S + vscol;

    #define STAGE(dst) do {                                  \
        gload_lds16(kg,          (dst) + w*512);             \
        gload_lds16(kg + 64*D,   (dst) + 4096 + w*512);      \
        gload_lds16(vg,          (dst) + 8192 + w*512);      \
        gload_lds16(vg + 32*S,   (dst) + 8192 + 4096 + w*512); \
        kg += (size_t)KVT * D; vg += KVT; } while (0)

    const int kh2 = kh * 2;
    auto compute = [&](const u16* base) {
        const u16* Kl = base;
        const u16* Vl = base + 8192;
        #pragma unroll
        for (int c = 0; c < 2; ++c) {
            const int ca = kh2 + c;
            // ---- QK for keys ca*32 .. ca*32+31 ----
            f32x16 p0, p1;
            {
                const u16* kr = &Kl[(ca*32 + q) << 6];
                bf16x8 k0 = *(const bf16x8*)&kr[((0*32 + hi*16) ^ rsw) >> 1];
                __builtin_amdgcn_s_setprio(1);
                p0 = __builtin_amdgcn_mfma_f32_32x32x16_bf16(k0, qf[0][0], zv, 0, 0, 0);
                p1 = __builtin_amdgcn_mfma_f32_32x32x16_bf16(k0, qf[1][0], zv, 0, 0, 0);
                #pragma unroll
                for (int cc = 1; cc < 4; ++cc) {
                    bf16x8 kf = *(const bf16x8*)&kr[((cc*32 + hi*16) ^ rsw) >> 1];
                    p0 = __builtin_amdgcn_mfma_f32_32x32x16_bf16(kf, qf[0][cc], p0, 0, 0, 0);
                    p1 = __builtin_amdgcn_mfma_f32_32x32x16_bf16(kf, qf[1][cc], p1, 0, 0, 0);
                }
                __builtin_amdgcn_s_setprio(0);
            }

            // ---- P = exp2(score), pack to bf16 fragments ----
            u32 W0[8], W1[8];
            #pragma unroll
            for (int j = 0; j < 8; ++j) {
                W0[j] = packbf(exp2_fast(p0[2*j]), exp2_fast(p0[2*j + 1]));
                W1[j] = packbf(exp2_fast(p1[2*j]), exp2_fast(p1[2*j + 1]));
            }
            plswap(W0[0], W0[2]); plswap(W0[1], W0[3]);
            plswap(W0[4], W0[6]); plswap(W0[5], W0[7]);
            plswap(W1[0], W1[2]); plswap(W1[1], W1[3]);
            plswap(W1[4], W1[6]); plswap(W1[5], W1[7]);
            bf16x8 pa0a, pa0b, pa1a, pa1b;
            {
                union { u32 u[4]; bf16x8 v; } pb;
                pb.u[0]=W0[0]; pb.u[1]=W0[1]; pb.u[2]=W0[2]; pb.u[3]=W0[3]; pa0a = pb.v;
                pb.u[0]=W0[4]; pb.u[1]=W0[5]; pb.u[2]=W0[6]; pb.u[3]=W0[7]; pa0b = pb.v;
                pb.u[0]=W1[0]; pb.u[1]=W1[1]; pb.u[2]=W1[2]; pb.u[3]=W1[3]; pa1a = pb.v;
                pb.u[0]=W1[4]; pb.u[1]=W1[5]; pb.u[2]=W1[6]; pb.u[3]=W1[7]; pa1b = pb.v;
            }

            // ---- lsum += ones^T x P ; po += Vt_frag x pa ----
            __builtin_amdgcn_s_setprio(1);
            lsum[0] = __builtin_amdgcn_mfma_f32_32x32x16_bf16(ones, pa0a, lsum[0], 0, 0, 0);
            lsum[1] = __builtin_amdgcn_mfma_f32_32x32x16_bf16(ones, pa1a, lsum[1], 0, 0, 0);
            lsum[0] = __builtin_amdgcn_mfma_f32_32x32x16_bf16(ones, pa0b, lsum[0], 0, 0, 0);
            lsum[1] = __builtin_amdgcn_mfma_f32_32x32x16_bf16(ones, pa1b, lsum[1], 0, 0, 0);
            #pragma unroll
            for (int kk = 0; kk < 2; ++kk) {
                int vb = ((ca*64 + kk*32 + hi*16) ^ vsw) >> 1;
                bf16x8 v0 = *(const bf16x8*)&Vl[(q << 7) + vb];
                bf16x8 v1 = *(const bf16x8*)&Vl[((32 + q) << 7) + vb];
                bf16x8 pq0 = kk ? pa0b : pa0a;
                bf16x8 pq1 = kk ? pa1b : pa1a;
                po[0] = __builtin_amdgcn_mfma_f32_32x32x16_bf16(v0, pq0, po[0], 0, 0, 0);
                po[1] = __builtin_amdgcn_mfma_f32_32x32x16_bf16(v1, pq0, po[1], 0, 0, 0);
                po[2] = __builtin_amdgcn_mfma_f32_32x32x16_bf16(v0, pq1, po[2], 0, 0, 0);
                po[3] = __builtin_amdgcn_mfma_f32_32x32x16_bf16(v1, pq1, po[3], 0, 0, 0);
            }
            __builtin_amdgcn_s_setprio(0);
        }
    };

    // prologue: stage tile 0
    STAGE(buf0);
    asm volatile("s_waitcnt vmcnt(0)" ::: "memory");
    __builtin_amdgcn_s_barrier();

    for (int ti = 0; ti < NT; ti += 2) {
        STAGE(buf1);                       // tile ti+1
        compute(buf0);                     // tile ti
        asm volatile("s_waitcnt vmcnt(0)" ::: "memory");
        __builtin_amdgcn_s_barrier();
        if (ti < NT - 2) STAGE(buf0);      // tile ti+2
        compute(buf1);                     // tile ti+1
        asm volatile("s_waitcnt vmcnt(0)" ::: "memory");
        __builtin_amdgcn_s_barrier();
    }
    #undef STAGE

    // ---- key-half combine: waves 4-7 add into waves 0-3 (pure sum) ----
    float* cb = (float*)smem;
    if (kh == 1) {
        #pragma unroll
        for (int i = 0; i < 16; ++i) {
            cb[wq4*2048 + i*64 + ll]        = po[0][i];
            cb[wq4*2048 + (16+i)*64 + ll]   = po[1][i];
        }
        cb[8192 + 0*256 + wq4*64 + ll] = lsum[0][0];
        cb[8192 + 1*256 + wq4*64 + ll] = lsum[1][0];
    }
    __syncthreads();
    if (kh == 0) {
        #pragma unroll
        for (int i = 0; i < 16; ++i) {
            po[0][i] += cb[wq4*2048 + i*64 + ll];
            po[1][i] += cb[wq4*2048 + (16+i)*64 + ll];
        }
        lsum[0][0] += cb[8192 + 0*256 + wq4*64 + ll];
        lsum[1][0] += cb[8192 + 1*256 + wq4*64 + ll];
    }
    __syncthreads();
    if (kh == 1) {
        #pragma unroll
        for (int i = 0; i < 16; ++i) {
            cb[wq4*2048 + i*64 + ll]        = po[2][i];
            cb[wq4*2048 + (16+i)*64 + ll]   = po[3][i];
        }
    }
    __syncthreads();
    if (kh == 0) {
        #pragma unroll
        for (int i = 0; i < 16; ++i) {
            po[2][i] += cb[wq4*2048 + i*64 + ll];
            po[3][i] += cb[wq4*2048 + (16+i)*64 + ll];
        }
    }
    __syncthreads();

    // ---- epilogue (waves 0-3): normalize + transpose via wave-local LDS ----
    if (kh == 0) {
        u16* ow = &smem[wq4 * 2304];   // 32 rows x 72 u16 per wave (wave-local)
        #pragma unroll
        for (int qg = 0; qg < 2; ++qg) {
            float inv = 1.f / lsum[qg][0];
            #pragma unroll
            for (int r = 0; r < 16; ++r) {
                int d0 = (r & 3) + 8 * (r >> 2) + 4 * hi;
                ow[q * 72 + d0]      = f2bf(po[qg*2 + 0][r] * inv);
                ow[q * 72 + 32 + d0] = f2bf(po[qg*2 + 1][r] * inv);
            }
            int row = ll >> 1, half = t & 1;
            const u16* orow = &ow[row * 72 + half * 32];
            u16* gp = &CTX[(size_t)(b*S + qbase + qg*32 + row) * D + h*DH + half * 32];
            #pragma unroll
            for (int i = 0; i < 4; ++i)
                *(bf16x8*)(gp + i * 8) = *(const bf16x8*)(orow + i * 8);
        }
    }
}

extern "C" void kernel_launch(void* const* d_in, const int* in_sizes, int n_in,
                              void* d_out, int out_size, void* d_ws, size_t ws_size,
                              hipStream_t stream)
{
    const float* x    = (const float*)d_in[0];
    const float* cosT = (const float*)d_in[1];
    const float* sinT = (const float*)d_in[2];
    const float* wq   = (const float*)d_in[3];
    const float* wk   = (const float*)d_in[4];
    const float* wv   = (const float*)d_in[5];
    const float* wo   = (const float*)d_in[6];
    float* out = (float*)d_out;

    const size_t MD = (size_t)M_TOT * D;
    const size_t WD = (size_t)D * D;

    u16* xb   = (u16*)d_ws;
    u16* Qb   = xb + MD;
    u16* Kb   = Qb + MD;
    u16* Vtb  = Kb + MD;
    u16* CTXb = Vtb + MD;
    u16* wqb  = CTXb + MD;
    u16* wkb  = wqb + WD;
    u16* wvb  = wkb + WD;
    u16* wob  = wvb + WD;

    // 1. fused bf16 casts (x + 4 weights in one launch)
    cvt_all_kernel<<<(int)((MD + 4*WD) / 8 / 256), 256, 0, stream>>>(
        x, wq, wk, wv, wo, xb, wqb, wkb, wvb, wob);

    // 2. fused QKV projections (z=0: Q rope+scale, z=1: K rope, z=2: V -> Vt transposed)
    gemm_mfma<1, 1><<<dim3(M_TOT / 128, D / 128, 3), 256, 0, stream>>>(
        xb, wqb, wkb, wvb, Qb, Kb, Vtb, cosT, sinT);

    // 3. attention (8-wave key-split blocks)
    attn_mfma<<<dim3(M_TOT / QBLK * H), 512, 0, stream>>>(Qb, Kb, Vtb, CTXb);

    // 4. output projection (fp32 out)
    gemm_mfma<0, 0><<<dim3(M_TOT / 128, D / 128, 1), 256, 0, stream>>>(
        CTXb, wob, nullptr, nullptr, out, nullptr, nullptr, nullptr, nullptr);
}

// Round 11
// 188.819 us; speedup vs baseline: 5.0886x; 5.0886x over previous
//
#include <hip/hip_runtime.h>
#include <hip/hip_bf16.h>
#include <stdint.h>

#define B 4
#define S 2048
#define D 1024
#define H 16
#define DH 64
#define M_TOT (B*S)
#define BH (B*H)

typedef unsigned short u16;
typedef unsigned int u32;
typedef __attribute__((ext_vector_type(4))) float f32x4;
typedef __attribute__((ext_vector_type(16))) float f32x16;
typedef __attribute__((ext_vector_type(8))) short bf16x8;
typedef __attribute__((ext_vector_type(2))) unsigned int u32x2;

typedef const __attribute__((address_space(1))) unsigned int* gp_t;
typedef __attribute__((address_space(3))) unsigned int* lp_t;

__device__ __forceinline__ void gload_lds16(const void* g, void* l) {
    __builtin_amdgcn_global_load_lds((gp_t)g, (lp_t)l, 16, 0, 0);
}

__device__ __forceinline__ float bf2f(u16 u) {
    u32 t = ((u32)u) << 16;
    float f; __builtin_memcpy(&f, &t, 4); return f;
}
__device__ __forceinline__ u16 f2bf(float f) {   // RTNE
    u32 u; __builtin_memcpy(&u, &f, 4);
    u += 0x7fffu + ((u >> 16) & 1u);
    return (u16)(u >> 16);
}
__device__ __forceinline__ u32 packbf(float lo, float hi_) {
    __hip_bfloat162 h = __float22bfloat162_rn(float2{lo, hi_});
    u32 r; __builtin_memcpy(&r, &h, 4); return r;
}

__device__ __forceinline__ float exp2_fast(float x) { return __builtin_amdgcn_exp2f(x); }

#if __has_builtin(__builtin_amdgcn_permlane32_swap)
__device__ __forceinline__ void plswap(u32& a, u32& bb) {
    u32x2 r = __builtin_amdgcn_permlane32_swap(a, bb, false, false);
    a = r.x; bb = r.y;
}
#else
__device__ __forceinline__ void plswap(u32& a, u32& bb) {
    int hi = (threadIdx.x >> 5) & 1;
    u32 ra = (u32)__shfl_xor((int)a, 32);
    u32 rb = (u32)__shfl_xor((int)bb, 32);
    u32 na = hi ? rb : a;
    u32 nb = hi ? bb : ra;
    a = na; bb = nb;
}
#endif

// ---------------- fused fp32 -> bf16 cast for x + 4 weights ----------------
__global__ __launch_bounds__(256)
void cvt_all_kernel(const float* __restrict__ x,
                    const float* __restrict__ wq, const float* __restrict__ wk,
                    const float* __restrict__ wv, const float* __restrict__ wo,
                    u16* __restrict__ xb, u16* __restrict__ wqb, u16* __restrict__ wkb,
                    u16* __restrict__ wvb, u16* __restrict__ wob)
{
    const size_t MD = (size_t)M_TOT * D;
    const size_t WD = (size_t)D * D;       // 2^20
    size_t i = ((size_t)blockIdx.x * 256 + threadIdx.x) * 8;
    const float* src; u16* dst; size_t off;
    if (i < MD) { src = x; dst = xb; off = i; }
    else {
        size_t j = i - MD;
        int wsel = (int)(j >> 20);
        off = j & (WD - 1);
        if      (wsel == 0) { src = wq; dst = wqb; }
        else if (wsel == 1) { src = wk; dst = wkb; }
        else if (wsel == 2) { src = wv; dst = wvb; }
        else                { src = wo; dst = wob; }
    }
    float4 a = *(const float4*)(src + off);
    float4 b = *(const float4*)(src + off + 4);
    union { u16 u[8]; bf16x8 v; } o;
    o.u[0] = f2bf(a.x); o.u[1] = f2bf(a.y); o.u[2] = f2bf(a.z); o.u[3] = f2bf(a.w);
    o.u[4] = f2bf(b.x); o.u[5] = f2bf(b.y); o.u[6] = f2bf(b.z); o.u[7] = f2bf(b.w);
    *(bf16x8*)(dst + off) = o.v;
}

// ---------------- bf16 MFMA GEMM (m97 structure) ----------------
// QKV mode (DO_ROPE=1): z=0 -> Q rope + cs2 scale; z=1 -> K rope;
// z=2 -> V written TRANSPOSED into Vt[(b*16+h)*64+dh][s] (vtrans fused).
template<int WRITE_BF16, int DO_ROPE>
__global__ __launch_bounds__(256)
void gemm_mfma(const u16* __restrict__ X,
               const u16* __restrict__ W0, const u16* __restrict__ W1, const u16* __restrict__ W2,
               void* Y0, void* Y1, void* Y2,
               const float* __restrict__ cosT, const float* __restrict__ sinT)
{
    __shared__ __align__(16) u16 Al[128 * 32];
    __shared__ __align__(16) u16 Bl[128 * 32];

    const u16* Wm = (blockIdx.z == 0) ? W0 : (blockIdx.z == 1) ? W1 : W2;
    void* Yv      = (blockIdx.z == 0) ? Y0 : (blockIdx.z == 1) ? Y1 : Y2;

    const int t = threadIdx.x;
    const int w = t >> 6, ll = t & 63;
    const int wr = w >> 1, wc = w & 1;
    const int g = ll >> 4, lc = ll & 15;
    const int m0 = blockIdx.x * 128, n0 = blockIdx.y * 128;

    const int srow = t >> 2;
    const int scol = (t & 3) * 8;

    const u16* Xa = X + (size_t)m0 * D;
    const u16* Wa = Wm + (size_t)n0 * D;

    f32x4 acc[4][4];
    #pragma unroll
    for (int i = 0; i < 4; ++i)
        #pragma unroll
        for (int j = 0; j < 4; ++j)
            acc[i][j] = (f32x4){0.f, 0.f, 0.f, 0.f};

    for (int k0 = 0; k0 < D; k0 += 32) {
        gload_lds16(Xa + (size_t)(srow)      * D + k0 + scol, &Al[(w * 64) * 8]);
        gload_lds16(Xa + (size_t)(64 + srow) * D + k0 + scol, &Al[(256 + w * 64) * 8]);
        gload_lds16(Wa + (size_t)(srow)      * D + k0 + scol, &Bl[(w * 64) * 8]);
        gload_lds16(Wa + (size_t)(64 + srow) * D + k0 + scol, &Bl[(256 + w * 64) * 8]);
        __syncthreads();

        bf16x8 af[4], bf[4];
        #pragma unroll
        for (int i = 0; i < 4; ++i)
            af[i] = *(const bf16x8*)&Al[(wr * 64 + i * 16 + lc) * 32 + g * 8];
        #pragma unroll
        for (int j = 0; j < 4; ++j)
            bf[j] = *(const bf16x8*)&Bl[(wc * 64 + j * 16 + lc) * 32 + g * 8];

        #pragma unroll
        for (int i = 0; i < 4; ++i)
            #pragma unroll
            for (int j = 0; j < 4; ++j)
                acc[i][j] = __builtin_amdgcn_mfma_f32_16x16x32_bf16(af[i], bf[j], acc[i][j], 0, 0, 0);
        __syncthreads();
    }

    if (DO_ROPE && blockIdx.z < 2) {
        const float scale = (blockIdx.z == 0) ? (0.125f * 1.44269504f) : 1.0f;
        u16* Y = (u16*)Yv;
        #pragma unroll
        for (int i = 0; i < 4; ++i)
            #pragma unroll
            for (int r = 0; r < 4; ++r) {
                int row = m0 + wr * 64 + i * 16 + g * 4 + r;
                int s = row & (S - 1);
                #pragma unroll
                for (int jh = 0; jh < 2; ++jh) {
                    float c  = cosT[s * DH + jh * 16 + lc];
                    float sn = sinT[s * DH + jh * 16 + lc];
                    float a0 = acc[i][jh][r], a1 = acc[i][jh + 2][r];
                    size_t base = (size_t)row * D + n0 + wc * 64;
                    Y[base + jh * 16 + lc]       = f2bf((a0 * c - a1 * sn) * scale);
                    Y[base + (jh + 2) * 16 + lc] = f2bf((a1 * c + a0 * sn) * scale);
                }
            }
    } else if (DO_ROPE) {
        // z==2: V projection, write transposed: Vt[(b*16 + col/64)*64 + col%64][s]
        u16* Y = (u16*)Yv;
        #pragma unroll
        for (int i = 0; i < 4; ++i)
            #pragma unroll
            for (int j = 0; j < 4; ++j) {
                int row = m0 + wr * 64 + i * 16 + g * 4;       // token index (r=0)
                int col = n0 + wc * 64 + j * 16 + lc;          // feature index
                int bt = row >> 11, s = row & (S - 1);
                size_t vtrow = (size_t)(bt * 16 + (col >> 6)) * 64 + (col & 63);
                u32 w0 = packbf(acc[i][j][0], acc[i][j][1]);
                u32 w1 = packbf(acc[i][j][2], acc[i][j][3]);
                u32x2 pr; pr.x = w0; pr.y = w1;
                *(u32x2*)&Y[vtrow * S + s] = pr;               // 4 consecutive s, 8B store
            }
    } else if (WRITE_BF16) {
        u16* Y = (u16*)Yv;
        #pragma unroll
        for (int i = 0; i < 4; ++i)
            #pragma unroll
            for (int j = 0; j < 4; ++j)
                #pragma unroll
                for (int r = 0; r < 4; ++r) {
                    int row = m0 + wr * 64 + i * 16 + g * 4 + r;
                    int col = n0 + wc * 64 + j * 16 + lc;
                    Y[(size_t)row * D + col] = f2bf(acc[i][j][r]);
                }
    } else {
        float* Y = (float*)Yv;
        #pragma unroll
        for (int i = 0; i < 4; ++i)
            #pragma unroll
            for (int j = 0; j < 4; ++j)
                #pragma unroll
                for (int r = 0; r < 4; ++r) {
                    int row = m0 + wr * 64 + i * 16 + g * 4 + r;
                    int col = n0 + wc * 64 + j * 16 + lc;
                    Y[(size_t)row * D + col] = acc[i][j][r];
                }
    }
}

// ---------------- MFMA flash attention: key-split 8-wave blocks ------------
// 512 threads = 8 waves: wq4 = w&3 picks the 64-q-row group, kh = w>>2 picks
// the key half of each staged 128-key tile. No-max softmax => partials
// combine by pure ADD at the end. __launch_bounds__(512,2): NO forced VGPR
// cap (R10's (512,4) capped regs at 64+AGPR and spilled 4GB to scratch);
// natural allocation ~116 VGPR -> 128-bucket -> 16 waves/CU via 2 blocks.
#define QBLK 256
#define KVT 128
#define NT (S / KVT)

__global__ __launch_bounds__(512, 2)
void attn_mfma(const u16* __restrict__ Q, const u16* __restrict__ Kg,
               const u16* __restrict__ Vt, u16* __restrict__ CTX)
{
    __shared__ __align__(16) u16 smem[32768];   // 2 x (K 16KB + V 16KB)

    const int t   = threadIdx.x;
    const int w   = t >> 6;          // 0..7
    const int wq4 = w & 3;           // q-wave
    const int kh  = w >> 2;          // key-half
    const int ll  = t & 63;
    const int q   = t & 31;
    const int hi  = (t >> 5) & 1;

    // XCD-chunked swizzle: 8 bh per XCD
    const int bid  = blockIdx.x;          // 0..511
    const int xcd  = bid & 7;
    const int slot = bid >> 3;            // 0..63
    const int bh   = xcd * 8 + (slot >> 3);
    const int qb   = slot & 7;
    const int b = bh >> 4, h = bh & 15;
    const int q0 = qb * QBLK;
    const int qbase = q0 + wq4 * 64;

    // Q as B-fragments for 2 q-groups (same for both key-halves)
    bf16x8 qf[2][4];
    #pragma unroll
    for (int qg = 0; qg < 2; ++qg) {
        const u16* qp = &Q[(size_t)(b*S + qbase + qg*32 + q) * D + h*DH + hi*8];
        qf[qg][0] = *(const bf16x8*)(qp);
        qf[qg][1] = *(const bf16x8*)(qp + 16);
        qf[qg][2] = *(const bf16x8*)(qp + 32);
        qf[qg][3] = *(const bf16x8*)(qp + 48);
    }

    bf16x8 ones;
    {
        union { u16 u[8]; bf16x8 v; } ou;
        #pragma unroll
        for (int i = 0; i < 8; ++i) ou.u[i] = 0x3f80;   // bf16 1.0
        ones = ou.v;
    }

    f32x16 po[4], lsum[2], zv;
    #pragma unroll
    for (int i = 0; i < 16; ++i) {
        po[0][i] = 0.f; po[1][i] = 0.f; po[2][i] = 0.f; po[3][i] = 0.f;
        lsum[0][i] = 0.f; lsum[1][i] = 0.f; zv[i] = 0.f;
    }

    // K staging (128B rows, 8 lanes/row): 512 thr x 16B = 64 rows/issue
    const int ksrow = t >> 3;                                 // 0..63
    const int kscol = (((t & 7) << 4) ^ ((ksrow & 7) << 4)) >> 1;
    // V staging (256B rows, 16 lanes/row): 32 rows/issue
    const int vsrow = t >> 4;                                 // 0..31
    const int vscol = (((t & 15) ^ (vsrow & 15)) << 3);       // u16 units
    const int rsw  = (q & 7) << 4;    // K read swizzle (bytes)
    const int vsw  = (q & 15) << 4;   // V read swizzle (bytes)

    u16* buf0 = smem;
    u16* buf1 = smem + 16384;

    const u16* kg = Kg + ((size_t)(b * S) + ksrow) * D + (size_t)h * DH + kscol;
    const u16* vg = Vt + ((size_t)bh * DH + vsrow) * S + vscol;

    #define STAGE(dst) do {                                  \
        gload_lds16(kg,          (dst) + w*512);             \
        gload_lds16(kg + 64*D,   (dst) + 4096 + w*512);      \
        gload_lds16(vg,          (dst) + 8192 + w*512);      \
        gload_lds16(vg + 32*S,   (dst) + 8192 + 4096 + w*512); \
        kg += (size_t)KVT * D; vg += KVT; } while (0)

    const int kh2 = kh * 2;
    auto compute = [&](const u16* base) {
        const u16* Kl = base;
        const u16* Vl = base + 8192;
        #pragma unroll
        for (int c = 0; c < 2; ++c) {
            const int ca = kh2 + c;
            // ---- QK for keys ca*32 .. ca*32+31 ----
            f32x16 p0, p1;
            {
                const u16* kr = &Kl[(ca*32 + q) << 6];
                bf16x8 k0 = *(const bf16x8*)&kr[((0*32 + hi*16) ^ rsw) >> 1];
                __builtin_amdgcn_s_setprio(1);
                p0 = __builtin_amdgcn_mfma_f32_32x32x16_bf16(k0, qf[0][0], zv, 0, 0, 0);
                p1 = __builtin_amdgcn_mfma_f32_32x32x16_bf16(k0, qf[1][0], zv, 0, 0, 0);
                #pragma unroll
                for (int cc = 1; cc < 4; ++cc) {
                    bf16x8 kf = *(const bf16x8*)&kr[((cc*32 + hi*16) ^ rsw) >> 1];
                    p0 = __builtin_amdgcn_mfma_f32_32x32x16_bf16(kf, qf[0][cc], p0, 0, 0, 0);
                    p1 = __builtin_amdgcn_mfma_f32_32x32x16_bf16(kf, qf[1][cc], p1, 0, 0, 0);
                }
                __builtin_amdgcn_s_setprio(0);
            }

            // ---- P = exp2(score), pack to bf16 fragments ----
            u32 W0[8], W1[8];
            #pragma unroll
            for (int j = 0; j < 8; ++j) {
                W0[j] = packbf(exp2_fast(p0[2*j]), exp2_fast(p0[2*j + 1]));
                W1[j] = packbf(exp2_fast(p1[2*j]), exp2_fast(p1[2*j + 1]));
            }
            plswap(W0[0], W0[2]); plswap(W0[1], W0[3]);
            plswap(W0[4], W0[6]); plswap(W0[5], W0[7]);
            plswap(W1[0], W1[2]); plswap(W1[1], W1[3]);
            plswap(W1[4], W1[6]); plswap(W1[5], W1[7]);
            bf16x8 pa0a, pa0b, pa1a, pa1b;
            {
                union { u32 u[4]; bf16x8 v; } pb;
                pb.u[0]=W0[0]; pb.u[1]=W0[1]; pb.u[2]=W0[2]; pb.u[3]=W0[3]; pa0a = pb.v;
                pb.u[0]=W0[4]; pb.u[1]=W0[5]; pb.u[2]=W0[6]; pb.u[3]=W0[7]; pa0b = pb.v;
                pb.u[0]=W1[0]; pb.u[1]=W1[1]; pb.u[2]=W1[2]; pb.u[3]=W1[3]; pa1a = pb.v;
                pb.u[0]=W1[4]; pb.u[1]=W1[5]; pb.u[2]=W1[6]; pb.u[3]=W1[7]; pa1b = pb.v;
            }

            // ---- lsum += ones^T x P ; po += Vt_frag x pa ----
            __builtin_amdgcn_s_setprio(1);
            lsum[0] = __builtin_amdgcn_mfma_f32_32x32x16_bf16(ones, pa0a, lsum[0], 0, 0, 0);
            lsum[1] = __builtin_amdgcn_mfma_f32_32x32x16_bf16(ones, pa1a, lsum[1], 0, 0, 0);
            lsum[0] = __builtin_amdgcn_mfma_f32_32x32x16_bf16(ones, pa0b, lsum[0], 0, 0, 0);
            lsum[1] = __builtin_amdgcn_mfma_f32_32x32x16_bf16(ones, pa1b, lsum[1], 0, 0, 0);
            #pragma unroll
            for (int kk = 0; kk < 2; ++kk) {
                int vb = ((ca*64 + kk*32 + hi*16) ^ vsw) >> 1;
                bf16x8 v0 = *(const bf16x8*)&Vl[(q << 7) + vb];
                bf16x8 v1 = *(const bf16x8*)&Vl[((32 + q) << 7) + vb];
                bf16x8 pq0 = kk ? pa0b : pa0a;
                bf16x8 pq1 = kk ? pa1b : pa1a;
                po[0] = __builtin_amdgcn_mfma_f32_32x32x16_bf16(v0, pq0, po[0], 0, 0, 0);
                po[1] = __builtin_amdgcn_mfma_f32_32x32x16_bf16(v1, pq0, po[1], 0, 0, 0);
                po[2] = __builtin_amdgcn_mfma_f32_32x32x16_bf16(v0, pq1, po[2], 0, 0, 0);
                po[3] = __builtin_amdgcn_mfma_f32_32x32x16_bf16(v1, pq1, po[3], 0, 0, 0);
            }
            __builtin_amdgcn_s_setprio(0);
        }
    };

    // prologue: stage tile 0
    STAGE(buf0);
    asm volatile("s_waitcnt vmcnt(0)" ::: "memory");
    __builtin_amdgcn_s_barrier();

    for (int ti = 0; ti < NT; ti += 2) {
        STAGE(buf1);                       // tile ti+1
        compute(buf0);                     // tile ti
        asm volatile("s_waitcnt vmcnt(0)" ::: "memory");
        __builtin_amdgcn_s_barrier();
        if (ti < NT - 2) STAGE(buf0);      // tile ti+2
        compute(buf1);                     // tile ti+1
        asm volatile("s_waitcnt vmcnt(0)" ::: "memory");
        __builtin_amdgcn_s_barrier();
    }
    #undef STAGE

    // ---- key-half combine: waves 4-7 add into waves 0-3 (pure sum) ----
    float* cb = (float*)smem;
    if (kh == 1) {
        #pragma unroll
        for (int i = 0; i < 16; ++i) {
            cb[wq4*2048 + i*64 + ll]        = po[0][i];
            cb[wq4*2048 + (16+i)*64 + ll]   = po[1][i];
        }
        cb[8192 + 0*256 + wq4*64 + ll] = lsum[0][0];
        cb[8192 + 1*256 + wq4*64 + ll] = lsum[1][0];
    }
    __syncthreads();
    if (kh == 0) {
        #pragma unroll
        for (int i = 0; i < 16; ++i) {
            po[0][i] += cb[wq4*2048 + i*64 + ll];
            po[1][i] += cb[wq4*2048 + (16+i)*64 + ll];
        }
        lsum[0][0] += cb[8192 + 0*256 + wq4*64 + ll];
        lsum[1][0] += cb[8192 + 1*256 + wq4*64 + ll];
    }
    __syncthreads();
    if (kh == 1) {
        #pragma unroll
        for (int i = 0; i < 16; ++i) {
            cb[wq4*2048 + i*64 + ll]        = po[2][i];
            cb[wq4*2048 + (16+i)*64 + ll]   = po[3][i];
        }
    }
    __syncthreads();
    if (kh == 0) {
        #pragma unroll
        for (int i = 0; i < 16; ++i) {
            po[2][i] += cb[wq4*2048 + i*64 + ll];
            po[3][i] += cb[wq4*2048 + (16+i)*64 + ll];
        }
    }
    __syncthreads();

    // ---- epilogue (waves 0-3): normalize + transpose via wave-local LDS ----
    if (kh == 0) {
        u16* ow = &smem[wq4 * 2304];   // 32 rows x 72 u16 per wave (wave-local)
        #pragma unroll
        for (int qg = 0; qg < 2; ++qg) {
            float inv = 1.f / lsum[qg][0];
            #pragma unroll
            for (int r = 0; r < 16; ++r) {
                int d0 = (r & 3) + 8 * (r >> 2) + 4 * hi;
                ow[q * 72 + d0]      = f2bf(po[qg*2 + 0][r] * inv);
                ow[q * 72 + 32 + d0] = f2bf(po[qg*2 + 1][r] * inv);
            }
            int row = ll >> 1, half = t & 1;
            const u16* orow = &ow[row * 72 + half * 32];
            u16* gp = &CTX[(size_t)(b*S + qbase + qg*32 + row) * D + h*DH + half * 32];
            #pragma unroll
            for (int i = 0; i < 4; ++i)
                *(bf16x8*)(gp + i * 8) = *(const bf16x8*)(orow + i * 8);
        }
    }
}

extern "C" void kernel_launch(void* const* d_in, const int* in_sizes, int n_in,
                              void* d_out, int out_size, void* d_ws, size_t ws_size,
                              hipStream_t stream)
{
    const float* x    = (const float*)d_in[0];
    const float* cosT = (const float*)d_in[1];
    const float* sinT = (const float*)d_in[2];
    const float* wq   = (const float*)d_in[3];
    const float* wk   = (const float*)d_in[4];
    const float* wv   = (const float*)d_in[5];
    const float* wo   = (const float*)d_in[6];
    float* out = (float*)d_out;

    const size_t MD = (size_t)M_TOT * D;
    const size_t WD = (size_t)D * D;

    u16* xb   = (u16*)d_ws;
    u16* Qb   = xb + MD;
    u16* Kb   = Qb + MD;
    u16* Vtb  = Kb + MD;
    u16* CTXb = Vtb + MD;
    u16* wqb  = CTXb + MD;
    u16* wkb  = wqb + WD;
    u16* wvb  = wkb + WD;
    u16* wob  = wvb + WD;

    // 1. fused bf16 casts (x + 4 weights in one launch)
    cvt_all_kernel<<<(int)((MD + 4*WD) / 8 / 256), 256, 0, stream>>>(
        x, wq, wk, wv, wo, xb, wqb, wkb, wvb, wob);

    // 2. fused QKV projections (z=0: Q rope+scale, z=1: K rope, z=2: V -> Vt transposed)
    gemm_mfma<1, 1><<<dim3(M_TOT / 128, D / 128, 3), 256, 0, stream>>>(
        xb, wqb, wkb, wvb, Qb, Kb, Vtb, cosT, sinT);

    // 3. attention (8-wave key-split blocks)
    attn_mfma<<<dim3(M_TOT / QBLK * H), 512, 0, stream>>>(Qb, Kb, Vtb, CTXb);

    // 4. output projection (fp32 out)
    gemm_mfma<0, 0><<<dim3(M_TOT / 128, D / 128, 1), 256, 0, stream>>>(
        CTXb, wob, nullptr, nullptr, out, nullptr, nullptr, nullptr, nullptr);
}

// Round 12
// 187.989 us; speedup vs baseline: 5.1111x; 1.0044x over previous
//
#include <hip/hip_runtime.h>
#include <hip/hip_bf16.h>
#include <stdint.h>

#define B 4
#define S 2048
#define D 1024
#define H 16
#define DH 64
#define M_TOT (B*S)
#define BH (B*H)

typedef unsigned short u16;
typedef unsigned int u32;
typedef __attribute__((ext_vector_type(4))) float f32x4;
typedef __attribute__((ext_vector_type(16))) float f32x16;
typedef __attribute__((ext_vector_type(8))) short bf16x8;
typedef __attribute__((ext_vector_type(2))) unsigned int u32x2;

typedef const __attribute__((address_space(1))) unsigned int* gp_t;
typedef __attribute__((address_space(3))) unsigned int* lp_t;

__device__ __forceinline__ void gload_lds16(const void* g, void* l) {
    __builtin_amdgcn_global_load_lds((gp_t)g, (lp_t)l, 16, 0, 0);
}

__device__ __forceinline__ float bf2f(u16 u) {
    u32 t = ((u32)u) << 16;
    float f; __builtin_memcpy(&f, &t, 4); return f;
}
__device__ __forceinline__ u16 f2bf(float f) {   // RTNE
    u32 u; __builtin_memcpy(&u, &f, 4);
    u += 0x7fffu + ((u >> 16) & 1u);
    return (u16)(u >> 16);
}
__device__ __forceinline__ u32 packbf(float lo, float hi_) {
    __hip_bfloat162 h = __float22bfloat162_rn(float2{lo, hi_});
    u32 r; __builtin_memcpy(&r, &h, 4); return r;
}

__device__ __forceinline__ float exp2_fast(float x) { return __builtin_amdgcn_exp2f(x); }

#if __has_builtin(__builtin_amdgcn_permlane32_swap)
__device__ __forceinline__ void plswap(u32& a, u32& bb) {
    u32x2 r = __builtin_amdgcn_permlane32_swap(a, bb, false, false);
    a = r.x; bb = r.y;
}
#else
__device__ __forceinline__ void plswap(u32& a, u32& bb) {
    int hi = (threadIdx.x >> 5) & 1;
    u32 ra = (u32)__shfl_xor((int)a, 32);
    u32 rb = (u32)__shfl_xor((int)bb, 32);
    u32 na = hi ? rb : a;
    u32 nb = hi ? bb : ra;
    a = na; bb = nb;
}
#endif

// ---------------- fused fp32 -> bf16 cast for x + 4 weights ----------------
__global__ __launch_bounds__(256)
void cvt_all_kernel(const float* __restrict__ x,
                    const float* __restrict__ wq, const float* __restrict__ wk,
                    const float* __restrict__ wv, const float* __restrict__ wo,
                    u16* __restrict__ xb, u16* __restrict__ wqb, u16* __restrict__ wkb,
                    u16* __restrict__ wvb, u16* __restrict__ wob)
{
    const size_t MD = (size_t)M_TOT * D;
    const size_t WD = (size_t)D * D;       // 2^20
    size_t i = ((size_t)blockIdx.x * 256 + threadIdx.x) * 8;
    const float* src; u16* dst; size_t off;
    if (i < MD) { src = x; dst = xb; off = i; }
    else {
        size_t j = i - MD;
        int wsel = (int)(j >> 20);
        off = j & (WD - 1);
        if      (wsel == 0) { src = wq; dst = wqb; }
        else if (wsel == 1) { src = wk; dst = wkb; }
        else if (wsel == 2) { src = wv; dst = wvb; }
        else                { src = wo; dst = wob; }
    }
    float4 a = *(const float4*)(src + off);
    float4 b = *(const float4*)(src + off + 4);
    union { u16 u[8]; bf16x8 v; } o;
    o.u[0] = f2bf(a.x); o.u[1] = f2bf(a.y); o.u[2] = f2bf(a.z); o.u[3] = f2bf(a.w);
    o.u[4] = f2bf(b.x); o.u[5] = f2bf(b.y); o.u[6] = f2bf(b.z); o.u[7] = f2bf(b.w);
    *(bf16x8*)(dst + off) = o.v;
}

// ---------------- bf16 MFMA GEMM (m97 structure) ----------------
// QKV mode (DO_ROPE=1): z=0 -> Q rope + cs2 scale; z=1 -> K rope;
// z=2 -> V written TRANSPOSED into Vt[(b*16+h)*64+dh][s] (vtrans fused).
template<int WRITE_BF16, int DO_ROPE>
__global__ __launch_bounds__(256)
void gemm_mfma(const u16* __restrict__ X,
               const u16* __restrict__ W0, const u16* __restrict__ W1, const u16* __restrict__ W2,
               void* Y0, void* Y1, void* Y2,
               const float* __restrict__ cosT, const float* __restrict__ sinT)
{
    __shared__ __align__(16) u16 Al[128 * 32];
    __shared__ __align__(16) u16 Bl[128 * 32];

    const u16* Wm = (blockIdx.z == 0) ? W0 : (blockIdx.z == 1) ? W1 : W2;
    void* Yv      = (blockIdx.z == 0) ? Y0 : (blockIdx.z == 1) ? Y1 : Y2;

    const int t = threadIdx.x;
    const int w = t >> 6, ll = t & 63;
    const int wr = w >> 1, wc = w & 1;
    const int g = ll >> 4, lc = ll & 15;
    const int m0 = blockIdx.x * 128, n0 = blockIdx.y * 128;

    const int srow = t >> 2;
    const int scol = (t & 3) * 8;

    const u16* Xa = X + (size_t)m0 * D;
    const u16* Wa = Wm + (size_t)n0 * D;

    f32x4 acc[4][4];
    #pragma unroll
    for (int i = 0; i < 4; ++i)
        #pragma unroll
        for (int j = 0; j < 4; ++j)
            acc[i][j] = (f32x4){0.f, 0.f, 0.f, 0.f};

    for (int k0 = 0; k0 < D; k0 += 32) {
        gload_lds16(Xa + (size_t)(srow)      * D + k0 + scol, &Al[(w * 64) * 8]);
        gload_lds16(Xa + (size_t)(64 + srow) * D + k0 + scol, &Al[(256 + w * 64) * 8]);
        gload_lds16(Wa + (size_t)(srow)      * D + k0 + scol, &Bl[(w * 64) * 8]);
        gload_lds16(Wa + (size_t)(64 + srow) * D + k0 + scol, &Bl[(256 + w * 64) * 8]);
        __syncthreads();

        bf16x8 af[4], bf[4];
        #pragma unroll
        for (int i = 0; i < 4; ++i)
            af[i] = *(const bf16x8*)&Al[(wr * 64 + i * 16 + lc) * 32 + g * 8];
        #pragma unroll
        for (int j = 0; j < 4; ++j)
            bf[j] = *(const bf16x8*)&Bl[(wc * 64 + j * 16 + lc) * 32 + g * 8];

        #pragma unroll
        for (int i = 0; i < 4; ++i)
            #pragma unroll
            for (int j = 0; j < 4; ++j)
                acc[i][j] = __builtin_amdgcn_mfma_f32_16x16x32_bf16(af[i], bf[j], acc[i][j], 0, 0, 0);
        __syncthreads();
    }

    if (DO_ROPE && blockIdx.z < 2) {
        const float scale = (blockIdx.z == 0) ? (0.125f * 1.44269504f) : 1.0f;
        u16* Y = (u16*)Yv;
        #pragma unroll
        for (int i = 0; i < 4; ++i)
            #pragma unroll
            for (int r = 0; r < 4; ++r) {
                int row = m0 + wr * 64 + i * 16 + g * 4 + r;
                int s = row & (S - 1);
                #pragma unroll
                for (int jh = 0; jh < 2; ++jh) {
                    float c  = cosT[s * DH + jh * 16 + lc];
                    float sn = sinT[s * DH + jh * 16 + lc];
                    float a0 = acc[i][jh][r], a1 = acc[i][jh + 2][r];
                    size_t base = (size_t)row * D + n0 + wc * 64;
                    Y[base + jh * 16 + lc]       = f2bf((a0 * c - a1 * sn) * scale);
                    Y[base + (jh + 2) * 16 + lc] = f2bf((a1 * c + a0 * sn) * scale);
                }
            }
    } else if (DO_ROPE) {
        // z==2: V projection, write transposed: Vt[(b*16 + col/64)*64 + col%64][s]
        u16* Y = (u16*)Yv;
        #pragma unroll
        for (int i = 0; i < 4; ++i)
            #pragma unroll
            for (int j = 0; j < 4; ++j) {
                int row = m0 + wr * 64 + i * 16 + g * 4;       // token index (r=0)
                int col = n0 + wc * 64 + j * 16 + lc;          // feature index
                int bt = row >> 11, s = row & (S - 1);
                size_t vtrow = (size_t)(bt * 16 + (col >> 6)) * 64 + (col & 63);
                u32 w0 = packbf(acc[i][j][0], acc[i][j][1]);
                u32 w1 = packbf(acc[i][j][2], acc[i][j][3]);
                u32x2 pr; pr.x = w0; pr.y = w1;
                *(u32x2*)&Y[vtrow * S + s] = pr;               // 4 consecutive s, 8B store
            }
    } else if (WRITE_BF16) {
        u16* Y = (u16*)Yv;
        #pragma unroll
        for (int i = 0; i < 4; ++i)
            #pragma unroll
            for (int j = 0; j < 4; ++j)
                #pragma unroll
                for (int r = 0; r < 4; ++r) {
                    int row = m0 + wr * 64 + i * 16 + g * 4 + r;
                    int col = n0 + wc * 64 + j * 16 + lc;
                    Y[(size_t)row * D + col] = f2bf(acc[i][j][r]);
                }
    } else {
        float* Y = (float*)Yv;
        #pragma unroll
        for (int i = 0; i < 4; ++i)
            #pragma unroll
            for (int j = 0; j < 4; ++j)
                #pragma unroll
                for (int r = 0; r < 4; ++r) {
                    int row = m0 + wr * 64 + i * 16 + g * 4 + r;
                    int col = n0 + wc * 64 + j * 16 + lc;
                    Y[(size_t)row * D + col] = acc[i][j][r];
                }
    }
}

// ---------------- MFMA flash attention: key-split 8-wave blocks ------------
// R12: all s_setprio REMOVED. Theory: prio-1 MFMA phases starved prio-0
// VALU phases of co-resident waves (T5 anti-pattern, m190) -> serial pipes.
// Everything else identical to R11.
#define QBLK 256
#define KVT 128
#define NT (S / KVT)

__global__ __launch_bounds__(512, 2)
void attn_mfma(const u16* __restrict__ Q, const u16* __restrict__ Kg,
               const u16* __restrict__ Vt, u16* __restrict__ CTX)
{
    __shared__ __align__(16) u16 smem[32768];   // 2 x (K 16KB + V 16KB)

    const int t   = threadIdx.x;
    const int w   = t >> 6;          // 0..7
    const int wq4 = w & 3;           // q-wave
    const int kh  = w >> 2;          // key-half
    const int ll  = t & 63;
    const int q   = t & 31;
    const int hi  = (t >> 5) & 1;

    // XCD-chunked swizzle: 8 bh per XCD
    const int bid  = blockIdx.x;          // 0..511
    const int xcd  = bid & 7;
    const int slot = bid >> 3;            // 0..63
    const int bh   = xcd * 8 + (slot >> 3);
    const int qb   = slot & 7;
    const int b = bh >> 4, h = bh & 15;
    const int q0 = qb * QBLK;
    const int qbase = q0 + wq4 * 64;

    // Q as B-fragments for 2 q-groups (same for both key-halves)
    bf16x8 qf[2][4];
    #pragma unroll
    for (int qg = 0; qg < 2; ++qg) {
        const u16* qp = &Q[(size_t)(b*S + qbase + qg*32 + q) * D + h*DH + hi*8];
        qf[qg][0] = *(const bf16x8*)(qp);
        qf[qg][1] = *(const bf16x8*)(qp + 16);
        qf[qg][2] = *(const bf16x8*)(qp + 32);
        qf[qg][3] = *(const bf16x8*)(qp + 48);
    }

    bf16x8 ones;
    {
        union { u16 u[8]; bf16x8 v; } ou;
        #pragma unroll
        for (int i = 0; i < 8; ++i) ou.u[i] = 0x3f80;   // bf16 1.0
        ones = ou.v;
    }

    f32x16 po[4], lsum[2], zv;
    #pragma unroll
    for (int i = 0; i < 16; ++i) {
        po[0][i] = 0.f; po[1][i] = 0.f; po[2][i] = 0.f; po[3][i] = 0.f;
        lsum[0][i] = 0.f; lsum[1][i] = 0.f; zv[i] = 0.f;
    }

    // K staging (128B rows, 8 lanes/row): 512 thr x 16B = 64 rows/issue
    const int ksrow = t >> 3;                                 // 0..63
    const int kscol = (((t & 7) << 4) ^ ((ksrow & 7) << 4)) >> 1;
    // V staging (256B rows, 16 lanes/row): 32 rows/issue
    const int vsrow = t >> 4;                                 // 0..31
    const int vscol = (((t & 15) ^ (vsrow & 15)) << 3);       // u16 units
    const int rsw  = (q & 7) << 4;    // K read swizzle (bytes)
    const int vsw  = (q & 15) << 4;   // V read swizzle (bytes)

    u16* buf0 = smem;
    u16* buf1 = smem + 16384;

    const u16* kg = Kg + ((size_t)(b * S) + ksrow) * D + (size_t)h * DH + kscol;
    const u16* vg = Vt + ((size_t)bh * DH + vsrow) * S + vscol;

    #define STAGE(dst) do {                                  \
        gload_lds16(kg,          (dst) + w*512);             \
        gload_lds16(kg + 64*D,   (dst) + 4096 + w*512);      \
        gload_lds16(vg,          (dst) + 8192 + w*512);      \
        gload_lds16(vg + 32*S,   (dst) + 8192 + 4096 + w*512); \
        kg += (size_t)KVT * D; vg += KVT; } while (0)

    const int kh2 = kh * 2;
    auto compute = [&](const u16* base) {
        const u16* Kl = base;
        const u16* Vl = base + 8192;
        #pragma unroll
        for (int c = 0; c < 2; ++c) {
            const int ca = kh2 + c;
            // ---- QK for keys ca*32 .. ca*32+31 ----
            f32x16 p0, p1;
            {
                const u16* kr = &Kl[(ca*32 + q) << 6];
                bf16x8 k0 = *(const bf16x8*)&kr[((0*32 + hi*16) ^ rsw) >> 1];
                p0 = __builtin_amdgcn_mfma_f32_32x32x16_bf16(k0, qf[0][0], zv, 0, 0, 0);
                p1 = __builtin_amdgcn_mfma_f32_32x32x16_bf16(k0, qf[1][0], zv, 0, 0, 0);
                #pragma unroll
                for (int cc = 1; cc < 4; ++cc) {
                    bf16x8 kf = *(const bf16x8*)&kr[((cc*32 + hi*16) ^ rsw) >> 1];
                    p0 = __builtin_amdgcn_mfma_f32_32x32x16_bf16(kf, qf[0][cc], p0, 0, 0, 0);
                    p1 = __builtin_amdgcn_mfma_f32_32x32x16_bf16(kf, qf[1][cc], p1, 0, 0, 0);
                }
            }

            // ---- P = exp2(score), pack to bf16 fragments ----
            u32 W0[8], W1[8];
            #pragma unroll
            for (int j = 0; j < 8; ++j) {
                W0[j] = packbf(exp2_fast(p0[2*j]), exp2_fast(p0[2*j + 1]));
                W1[j] = packbf(exp2_fast(p1[2*j]), exp2_fast(p1[2*j + 1]));
            }
            plswap(W0[0], W0[2]); plswap(W0[1], W0[3]);
            plswap(W0[4], W0[6]); plswap(W0[5], W0[7]);
            plswap(W1[0], W1[2]); plswap(W1[1], W1[3]);
            plswap(W1[4], W1[6]); plswap(W1[5], W1[7]);
            bf16x8 pa0a, pa0b, pa1a, pa1b;
            {
                union { u32 u[4]; bf16x8 v; } pb;
                pb.u[0]=W0[0]; pb.u[1]=W0[1]; pb.u[2]=W0[2]; pb.u[3]=W0[3]; pa0a = pb.v;
                pb.u[0]=W0[4]; pb.u[1]=W0[5]; pb.u[2]=W0[6]; pb.u[3]=W0[7]; pa0b = pb.v;
                pb.u[0]=W1[0]; pb.u[1]=W1[1]; pb.u[2]=W1[2]; pb.u[3]=W1[3]; pa1a = pb.v;
                pb.u[0]=W1[4]; pb.u[1]=W1[5]; pb.u[2]=W1[6]; pb.u[3]=W1[7]; pa1b = pb.v;
            }

            // ---- lsum += ones^T x P ; po += Vt_frag x pa ----
            lsum[0] = __builtin_amdgcn_mfma_f32_32x32x16_bf16(ones, pa0a, lsum[0], 0, 0, 0);
            lsum[1] = __builtin_amdgcn_mfma_f32_32x32x16_bf16(ones, pa1a, lsum[1], 0, 0, 0);
            lsum[0] = __builtin_amdgcn_mfma_f32_32x32x16_bf16(ones, pa0b, lsum[0], 0, 0, 0);
            lsum[1] = __builtin_amdgcn_mfma_f32_32x32x16_bf16(ones, pa1b, lsum[1], 0, 0, 0);
            #pragma unroll
            for (int kk = 0; kk < 2; ++kk) {
                int vb = ((ca*64 + kk*32 + hi*16) ^ vsw) >> 1;
                bf16x8 v0 = *(const bf16x8*)&Vl[(q << 7) + vb];
                bf16x8 v1 = *(const bf16x8*)&Vl[((32 + q) << 7) + vb];
                bf16x8 pq0 = kk ? pa0b : pa0a;
                bf16x8 pq1 = kk ? pa1b : pa1a;
                po[0] = __builtin_amdgcn_mfma_f32_32x32x16_bf16(v0, pq0, po[0], 0, 0, 0);
                po[1] = __builtin_amdgcn_mfma_f32_32x32x16_bf16(v1, pq0, po[1], 0, 0, 0);
                po[2] = __builtin_amdgcn_mfma_f32_32x32x16_bf16(v0, pq1, po[2], 0, 0, 0);
                po[3] = __builtin_amdgcn_mfma_f32_32x32x16_bf16(v1, pq1, po[3], 0, 0, 0);
            }
        }
    };

    // prologue: stage tile 0
    STAGE(buf0);
    asm volatile("s_waitcnt vmcnt(0)" ::: "memory");
    __builtin_amdgcn_s_barrier();

    for (int ti = 0; ti < NT; ti += 2) {
        STAGE(buf1);                       // tile ti+1
        compute(buf0);                     // tile ti
        asm volatile("s_waitcnt vmcnt(0)" ::: "memory");
        __builtin_amdgcn_s_barrier();
        if (ti < NT - 2) STAGE(buf0);      // tile ti+2
        compute(buf1);                     // tile ti+1
        asm volatile("s_waitcnt vmcnt(0)" ::: "memory");
        __builtin_amdgcn_s_barrier();
    }
    #undef STAGE

    // ---- key-half combine: waves 4-7 add into waves 0-3 (pure sum) ----
    float* cb = (float*)smem;
    if (kh == 1) {
        #pragma unroll
        for (int i = 0; i < 16; ++i) {
            cb[wq4*2048 + i*64 + ll]        = po[0][i];
            cb[wq4*2048 + (16+i)*64 + ll]   = po[1][i];
        }
        cb[8192 + 0*256 + wq4*64 + ll] = lsum[0][0];
        cb[8192 + 1*256 + wq4*64 + ll] = lsum[1][0];
    }
    __syncthreads();
    if (kh == 0) {
        #pragma unroll
        for (int i = 0; i < 16; ++i) {
            po[0][i] += cb[wq4*2048 + i*64 + ll];
            po[1][i] += cb[wq4*2048 + (16+i)*64 + ll];
        }
        lsum[0][0] += cb[8192 + 0*256 + wq4*64 + ll];
        lsum[1][0] += cb[8192 + 1*256 + wq4*64 + ll];
    }
    __syncthreads();
    if (kh == 1) {
        #pragma unroll
        for (int i = 0; i < 16; ++i) {
            cb[wq4*2048 + i*64 + ll]        = po[2][i];
            cb[wq4*2048 + (16+i)*64 + ll]   = po[3][i];
        }
    }
    __syncthreads();
    if (kh == 0) {
        #pragma unroll
        for (int i = 0; i < 16; ++i) {
            po[2][i] += cb[wq4*2048 + i*64 + ll];
            po[3][i] += cb[wq4*2048 + (16+i)*64 + ll];
        }
    }
    __syncthreads();

    // ---- epilogue (waves 0-3): normalize + transpose via wave-local LDS ----
    if (kh == 0) {
        u16* ow = &smem[wq4 * 2304];   // 32 rows x 72 u16 per wave (wave-local)
        #pragma unroll
        for (int qg = 0; qg < 2; ++qg) {
            float inv = 1.f / lsum[qg][0];
            #pragma unroll
            for (int r = 0; r < 16; ++r) {
                int d0 = (r & 3) + 8 * (r >> 2) + 4 * hi;
                ow[q * 72 + d0]      = f2bf(po[qg*2 + 0][r] * inv);
                ow[q * 72 + 32 + d0] = f2bf(po[qg*2 + 1][r] * inv);
            }
            int row = ll >> 1, half = t & 1;
            const u16* orow = &ow[row * 72 + half * 32];
            u16* gp = &CTX[(size_t)(b*S + qbase + qg*32 + row) * D + h*DH + half * 32];
            #pragma unroll
            for (int i = 0; i < 4; ++i)
                *(bf16x8*)(gp + i * 8) = *(const bf16x8*)(orow + i * 8);
        }
    }
}

extern "C" void kernel_launch(void* const* d_in, const int* in_sizes, int n_in,
                              void* d_out, int out_size, void* d_ws, size_t ws_size,
                              hipStream_t stream)
{
    const float* x    = (const float*)d_in[0];
    const float* cosT = (const float*)d_in[1];
    const float* sinT = (const float*)d_in[2];
    const float* wq   = (const float*)d_in[3];
    const float* wk   = (const float*)d_in[4];
    const float* wv   = (const float*)d_in[5];
    const float* wo   = (const float*)d_in[6];
    float* out = (float*)d_out;

    const size_t MD = (size_t)M_TOT * D;
    const size_t WD = (size_t)D * D;

    u16* xb   = (u16*)d_ws;
    u16* Qb   = xb + MD;
    u16* Kb   = Qb + MD;
    u16* Vtb  = Kb + MD;
    u16* CTXb = Vtb + MD;
    u16* wqb  = CTXb + MD;
    u16* wkb  = wqb + WD;
    u16* wvb  = wkb + WD;
    u16* wob  = wvb + WD;

    // 1. fused bf16 casts (x + 4 weights in one launch)
    cvt_all_kernel<<<(int)((MD + 4*WD) / 8 / 256), 256, 0, stream>>>(
        x, wq, wk, wv, wo, xb, wqb, wkb, wvb, wob);

    // 2. fused QKV projections (z=0: Q rope+scale, z=1: K rope, z=2: V -> Vt transposed)
    gemm_mfma<1, 1><<<dim3(M_TOT / 128, D / 128, 3), 256, 0, stream>>>(
        xb, wqb, wkb, wvb, Qb, Kb, Vtb, cosT, sinT);

    // 3. attention (8-wave key-split blocks, no setprio)
    attn_mfma<<<dim3(M_TOT / QBLK * H), 512, 0, stream>>>(Qb, Kb, Vtb, CTXb);

    // 4. output projection (fp32 out)
    gemm_mfma<0, 0><<<dim3(M_TOT / 128, D / 128, 1), 256, 0, stream>>>(
        CTXb, wob, nullptr, nullptr, out, nullptr, nullptr, nullptr, nullptr);
}

// Round 13
// 186.844 us; speedup vs baseline: 5.1424x; 1.0061x over previous
//
#include <hip/hip_runtime.h>
#include <hip/hip_bf16.h>
#include <stdint.h>

#define B 4
#define S 2048
#define D 1024
#define H 16
#define DH 64
#define M_TOT (B*S)
#define BH (B*H)

typedef unsigned short u16;
typedef unsigned int u32;
typedef __attribute__((ext_vector_type(4))) float f32x4;
typedef __attribute__((ext_vector_type(16))) float f32x16;
typedef __attribute__((ext_vector_type(8))) short bf16x8;
typedef __attribute__((ext_vector_type(2))) unsigned int u32x2;

typedef const __attribute__((address_space(1))) unsigned int* gp_t;
typedef __attribute__((address_space(3))) unsigned int* lp_t;

__device__ __forceinline__ void gload_lds16(const void* g, void* l) {
    __builtin_amdgcn_global_load_lds((gp_t)g, (lp_t)l, 16, 0, 0);
}

__device__ __forceinline__ float bf2f(u16 u) {
    u32 t = ((u32)u) << 16;
    float f; __builtin_memcpy(&f, &t, 4); return f;
}
__device__ __forceinline__ u16 f2bf(float f) {   // RTNE
    u32 u; __builtin_memcpy(&u, &f, 4);
    u += 0x7fffu + ((u >> 16) & 1u);
    return (u16)(u >> 16);
}
__device__ __forceinline__ u32 packbf(float lo, float hi_) {
    __hip_bfloat162 h = __float22bfloat162_rn(float2{lo, hi_});
    u32 r; __builtin_memcpy(&r, &h, 4); return r;
}

__device__ __forceinline__ float exp2_fast(float x) { return __builtin_amdgcn_exp2f(x); }

#if __has_builtin(__builtin_amdgcn_permlane32_swap)
__device__ __forceinline__ void plswap(u32& a, u32& bb) {
    u32x2 r = __builtin_amdgcn_permlane32_swap(a, bb, false, false);
    a = r.x; bb = r.y;
}
#else
__device__ __forceinline__ void plswap(u32& a, u32& bb) {
    int hi = (threadIdx.x >> 5) & 1;
    u32 ra = (u32)__shfl_xor((int)a, 32);
    u32 rb = (u32)__shfl_xor((int)bb, 32);
    u32 na = hi ? rb : a;
    u32 nb = hi ? bb : ra;
    a = na; bb = nb;
}
#endif

// ---------------- fused fp32 -> bf16 cast for x + 4 weights ----------------
__global__ __launch_bounds__(256)
void cvt_all_kernel(const float* __restrict__ x,
                    const float* __restrict__ wq, const float* __restrict__ wk,
                    const float* __restrict__ wv, const float* __restrict__ wo,
                    u16* __restrict__ xb, u16* __restrict__ wqb, u16* __restrict__ wkb,
                    u16* __restrict__ wvb, u16* __restrict__ wob)
{
    const size_t MD = (size_t)M_TOT * D;
    const size_t WD = (size_t)D * D;       // 2^20
    size_t i = ((size_t)blockIdx.x * 256 + threadIdx.x) * 8;
    const float* src; u16* dst; size_t off;
    if (i < MD) { src = x; dst = xb; off = i; }
    else {
        size_t j = i - MD;
        int wsel = (int)(j >> 20);
        off = j & (WD - 1);
        if      (wsel == 0) { src = wq; dst = wqb; }
        else if (wsel == 1) { src = wk; dst = wkb; }
        else if (wsel == 2) { src = wv; dst = wvb; }
        else                { src = wo; dst = wob; }
    }
    float4 a = *(const float4*)(src + off);
    float4 b = *(const float4*)(src + off + 4);
    union { u16 u[8]; bf16x8 v; } o;
    o.u[0] = f2bf(a.x); o.u[1] = f2bf(a.y); o.u[2] = f2bf(a.z); o.u[3] = f2bf(a.w);
    o.u[4] = f2bf(b.x); o.u[5] = f2bf(b.y); o.u[6] = f2bf(b.z); o.u[7] = f2bf(b.w);
    *(bf16x8*)(dst + off) = o.v;
}

// ---------------- bf16 MFMA GEMM (m97 structure) ----------------
// QKV mode (DO_ROPE=1): z=0 -> Q rope + cs2 scale; z=1 -> K rope;
// z=2 -> V written TRANSPOSED into Vt[(b*16+h)*64+dh][s] (vtrans fused).
template<int WRITE_BF16, int DO_ROPE>
__global__ __launch_bounds__(256)
void gemm_mfma(const u16* __restrict__ X,
               const u16* __restrict__ W0, const u16* __restrict__ W1, const u16* __restrict__ W2,
               void* Y0, void* Y1, void* Y2,
               const float* __restrict__ cosT, const float* __restrict__ sinT)
{
    __shared__ __align__(16) u16 Al[128 * 32];
    __shared__ __align__(16) u16 Bl[128 * 32];

    const u16* Wm = (blockIdx.z == 0) ? W0 : (blockIdx.z == 1) ? W1 : W2;
    void* Yv      = (blockIdx.z == 0) ? Y0 : (blockIdx.z == 1) ? Y1 : Y2;

    const int t = threadIdx.x;
    const int w = t >> 6, ll = t & 63;
    const int wr = w >> 1, wc = w & 1;
    const int g = ll >> 4, lc = ll & 15;
    const int m0 = blockIdx.x * 128, n0 = blockIdx.y * 128;

    const int srow = t >> 2;
    const int scol = (t & 3) * 8;

    const u16* Xa = X + (size_t)m0 * D;
    const u16* Wa = Wm + (size_t)n0 * D;

    f32x4 acc[4][4];
    #pragma unroll
    for (int i = 0; i < 4; ++i)
        #pragma unroll
        for (int j = 0; j < 4; ++j)
            acc[i][j] = (f32x4){0.f, 0.f, 0.f, 0.f};

    for (int k0 = 0; k0 < D; k0 += 32) {
        gload_lds16(Xa + (size_t)(srow)      * D + k0 + scol, &Al[(w * 64) * 8]);
        gload_lds16(Xa + (size_t)(64 + srow) * D + k0 + scol, &Al[(256 + w * 64) * 8]);
        gload_lds16(Wa + (size_t)(srow)      * D + k0 + scol, &Bl[(w * 64) * 8]);
        gload_lds16(Wa + (size_t)(64 + srow) * D + k0 + scol, &Bl[(256 + w * 64) * 8]);
        __syncthreads();

        bf16x8 af[4], bf[4];
        #pragma unroll
        for (int i = 0; i < 4; ++i)
            af[i] = *(const bf16x8*)&Al[(wr * 64 + i * 16 + lc) * 32 + g * 8];
        #pragma unroll
        for (int j = 0; j < 4; ++j)
            bf[j] = *(const bf16x8*)&Bl[(wc * 64 + j * 16 + lc) * 32 + g * 8];

        #pragma unroll
        for (int i = 0; i < 4; ++i)
            #pragma unroll
            for (int j = 0; j < 4; ++j)
                acc[i][j] = __builtin_amdgcn_mfma_f32_16x16x32_bf16(af[i], bf[j], acc[i][j], 0, 0, 0);
        __syncthreads();
    }

    if (DO_ROPE && blockIdx.z < 2) {
        const float scale = (blockIdx.z == 0) ? (0.125f * 1.44269504f) : 1.0f;
        u16* Y = (u16*)Yv;
        #pragma unroll
        for (int i = 0; i < 4; ++i)
            #pragma unroll
            for (int r = 0; r < 4; ++r) {
                int row = m0 + wr * 64 + i * 16 + g * 4 + r;
                int s = row & (S - 1);
                #pragma unroll
                for (int jh = 0; jh < 2; ++jh) {
                    float c  = cosT[s * DH + jh * 16 + lc];
                    float sn = sinT[s * DH + jh * 16 + lc];
                    float a0 = acc[i][jh][r], a1 = acc[i][jh + 2][r];
                    size_t base = (size_t)row * D + n0 + wc * 64;
                    Y[base + jh * 16 + lc]       = f2bf((a0 * c - a1 * sn) * scale);
                    Y[base + (jh + 2) * 16 + lc] = f2bf((a1 * c + a0 * sn) * scale);
                }
            }
    } else if (DO_ROPE) {
        // z==2: V projection, write transposed: Vt[(b*16 + col/64)*64 + col%64][s]
        u16* Y = (u16*)Yv;
        #pragma unroll
        for (int i = 0; i < 4; ++i)
            #pragma unroll
            for (int j = 0; j < 4; ++j) {
                int row = m0 + wr * 64 + i * 16 + g * 4;       // token index (r=0)
                int col = n0 + wc * 64 + j * 16 + lc;          // feature index
                int bt = row >> 11, s = row & (S - 1);
                size_t vtrow = (size_t)(bt * 16 + (col >> 6)) * 64 + (col & 63);
                u32 w0 = packbf(acc[i][j][0], acc[i][j][1]);
                u32 w1 = packbf(acc[i][j][2], acc[i][j][3]);
                u32x2 pr; pr.x = w0; pr.y = w1;
                *(u32x2*)&Y[vtrow * S + s] = pr;               // 4 consecutive s, 8B store
            }
    } else if (WRITE_BF16) {
        u16* Y = (u16*)Yv;
        #pragma unroll
        for (int i = 0; i < 4; ++i)
            #pragma unroll
            for (int j = 0; j < 4; ++j)
                #pragma unroll
                for (int r = 0; r < 4; ++r) {
                    int row = m0 + wr * 64 + i * 16 + g * 4 + r;
                    int col = n0 + wc * 64 + j * 16 + lc;
                    Y[(size_t)row * D + col] = f2bf(acc[i][j][r]);
                }
    } else {
        float* Y = (float*)Yv;
        #pragma unroll
        for (int i = 0; i < 4; ++i)
            #pragma unroll
            for (int j = 0; j < 4; ++j)
                #pragma unroll
                for (int r = 0; r < 4; ++r) {
                    int row = m0 + wr * 64 + i * 16 + g * 4 + r;
                    int col = n0 + wc * 64 + j * 16 + lc;
                    Y[(size_t)row * D + col] = acc[i][j][r];
                }
    }
}

// ---------------- MFMA flash attention: key-split 8-wave blocks ------------
// R13: lsum via VALU (in the exp/pack loop) instead of 8 ones-row MFMAs/tile
// (-20% matrix-pipe work). Sums are rescale-free => cross-half/key-half
// combines defer to the end. Frees 36 VGPR (no lsum f32x16[2], no ones).
#define QBLK 256
#define KVT 128
#define NT (S / KVT)

__global__ __launch_bounds__(512, 2)
void attn_mfma(const u16* __restrict__ Q, const u16* __restrict__ Kg,
               const u16* __restrict__ Vt, u16* __restrict__ CTX)
{
    __shared__ __align__(16) u16 smem[32768];   // 2 x (K 16KB + V 16KB)

    const int t   = threadIdx.x;
    const int w   = t >> 6;          // 0..7
    const int wq4 = w & 3;           // q-wave
    const int kh  = w >> 2;          // key-half
    const int ll  = t & 63;
    const int q   = t & 31;
    const int hi  = (t >> 5) & 1;

    // XCD-chunked swizzle: 8 bh per XCD
    const int bid  = blockIdx.x;          // 0..511
    const int xcd  = bid & 7;
    const int slot = bid >> 3;            // 0..63
    const int bh   = xcd * 8 + (slot >> 3);
    const int qb   = slot & 7;
    const int b = bh >> 4, h = bh & 15;
    const int q0 = qb * QBLK;
    const int qbase = q0 + wq4 * 64;

    // Q as B-fragments for 2 q-groups (same for both key-halves)
    bf16x8 qf[2][4];
    #pragma unroll
    for (int qg = 0; qg < 2; ++qg) {
        const u16* qp = &Q[(size_t)(b*S + qbase + qg*32 + q) * D + h*DH + hi*8];
        qf[qg][0] = *(const bf16x8*)(qp);
        qf[qg][1] = *(const bf16x8*)(qp + 16);
        qf[qg][2] = *(const bf16x8*)(qp + 32);
        qf[qg][3] = *(const bf16x8*)(qp + 48);
    }

    f32x16 po[4], zv;
    float ls0 = 0.f, ls1 = 0.f;
    #pragma unroll
    for (int i = 0; i < 16; ++i) {
        po[0][i] = 0.f; po[1][i] = 0.f; po[2][i] = 0.f; po[3][i] = 0.f;
        zv[i] = 0.f;
    }

    // K staging (128B rows, 8 lanes/row): 512 thr x 16B = 64 rows/issue
    const int ksrow = t >> 3;                                 // 0..63
    const int kscol = (((t & 7) << 4) ^ ((ksrow & 7) << 4)) >> 1;
    // V staging (256B rows, 16 lanes/row): 32 rows/issue
    const int vsrow = t >> 4;                                 // 0..31
    const int vscol = (((t & 15) ^ (vsrow & 15)) << 3);       // u16 units
    const int rsw  = (q & 7) << 4;    // K read swizzle (bytes)
    const int vsw  = (q & 15) << 4;   // V read swizzle (bytes)

    u16* buf0 = smem;
    u16* buf1 = smem + 16384;

    const u16* kg = Kg + ((size_t)(b * S) + ksrow) * D + (size_t)h * DH + kscol;
    const u16* vg = Vt + ((size_t)bh * DH + vsrow) * S + vscol;

    #define STAGE(dst) do {                                  \
        gload_lds16(kg,          (dst) + w*512);             \
        gload_lds16(kg + 64*D,   (dst) + 4096 + w*512);      \
        gload_lds16(vg,          (dst) + 8192 + w*512);      \
        gload_lds16(vg + 32*S,   (dst) + 8192 + 4096 + w*512); \
        kg += (size_t)KVT * D; vg += KVT; } while (0)

    const int kh2 = kh * 2;
    auto compute = [&](const u16* base) {
        const u16* Kl = base;
        const u16* Vl = base + 8192;
        #pragma unroll
        for (int c = 0; c < 2; ++c) {
            const int ca = kh2 + c;
            // ---- QK for keys ca*32 .. ca*32+31 ----
            f32x16 p0, p1;
            {
                const u16* kr = &Kl[(ca*32 + q) << 6];
                bf16x8 k0 = *(const bf16x8*)&kr[((0*32 + hi*16) ^ rsw) >> 1];
                p0 = __builtin_amdgcn_mfma_f32_32x32x16_bf16(k0, qf[0][0], zv, 0, 0, 0);
                p1 = __builtin_amdgcn_mfma_f32_32x32x16_bf16(k0, qf[1][0], zv, 0, 0, 0);
                #pragma unroll
                for (int cc = 1; cc < 4; ++cc) {
                    bf16x8 kf = *(const bf16x8*)&kr[((cc*32 + hi*16) ^ rsw) >> 1];
                    p0 = __builtin_amdgcn_mfma_f32_32x32x16_bf16(kf, qf[0][cc], p0, 0, 0, 0);
                    p1 = __builtin_amdgcn_mfma_f32_32x32x16_bf16(kf, qf[1][cc], p1, 0, 0, 0);
                }
            }

            // ---- P = exp2(score), pack + accumulate row-sums in VALU ----
            u32 W0[8], W1[8];
            #pragma unroll
            for (int j = 0; j < 8; ++j) {
                float a0 = exp2_fast(p0[2*j]),  b0 = exp2_fast(p0[2*j + 1]);
                float a1 = exp2_fast(p1[2*j]),  b1 = exp2_fast(p1[2*j + 1]);
                ls0 += a0 + b0;
                ls1 += a1 + b1;
                W0[j] = packbf(a0, b0);
                W1[j] = packbf(a1, b1);
            }
            plswap(W0[0], W0[2]); plswap(W0[1], W0[3]);
            plswap(W0[4], W0[6]); plswap(W0[5], W0[7]);
            plswap(W1[0], W1[2]); plswap(W1[1], W1[3]);
            plswap(W1[4], W1[6]); plswap(W1[5], W1[7]);
            bf16x8 pa0a, pa0b, pa1a, pa1b;
            {
                union { u32 u[4]; bf16x8 v; } pb;
                pb.u[0]=W0[0]; pb.u[1]=W0[1]; pb.u[2]=W0[2]; pb.u[3]=W0[3]; pa0a = pb.v;
                pb.u[0]=W0[4]; pb.u[1]=W0[5]; pb.u[2]=W0[6]; pb.u[3]=W0[7]; pa0b = pb.v;
                pb.u[0]=W1[0]; pb.u[1]=W1[1]; pb.u[2]=W1[2]; pb.u[3]=W1[3]; pa1a = pb.v;
                pb.u[0]=W1[4]; pb.u[1]=W1[5]; pb.u[2]=W1[6]; pb.u[3]=W1[7]; pa1b = pb.v;
            }

            // ---- PV: po += Vt_frag x pa ----
            #pragma unroll
            for (int kk = 0; kk < 2; ++kk) {
                int vb = ((ca*64 + kk*32 + hi*16) ^ vsw) >> 1;
                bf16x8 v0 = *(const bf16x8*)&Vl[(q << 7) + vb];
                bf16x8 v1 = *(const bf16x8*)&Vl[((32 + q) << 7) + vb];
                bf16x8 pq0 = kk ? pa0b : pa0a;
                bf16x8 pq1 = kk ? pa1b : pa1a;
                po[0] = __builtin_amdgcn_mfma_f32_32x32x16_bf16(v0, pq0, po[0], 0, 0, 0);
                po[1] = __builtin_amdgcn_mfma_f32_32x32x16_bf16(v1, pq0, po[1], 0, 0, 0);
                po[2] = __builtin_amdgcn_mfma_f32_32x32x16_bf16(v0, pq1, po[2], 0, 0, 0);
                po[3] = __builtin_amdgcn_mfma_f32_32x32x16_bf16(v1, pq1, po[3], 0, 0, 0);
            }
        }
    };

    // prologue: stage tile 0
    STAGE(buf0);
    asm volatile("s_waitcnt vmcnt(0)" ::: "memory");
    __builtin_amdgcn_s_barrier();

    for (int ti = 0; ti < NT; ti += 2) {
        STAGE(buf1);                       // tile ti+1
        compute(buf0);                     // tile ti
        asm volatile("s_waitcnt vmcnt(0)" ::: "memory");
        __builtin_amdgcn_s_barrier();
        if (ti < NT - 2) STAGE(buf0);      // tile ti+2
        compute(buf1);                     // tile ti+1
        asm volatile("s_waitcnt vmcnt(0)" ::: "memory");
        __builtin_amdgcn_s_barrier();
    }
    #undef STAGE

    // ---- key-half combine: waves 4-7 add into waves 0-3 (pure sum) ----
    float* cb = (float*)smem;
    if (kh == 1) {
        #pragma unroll
        for (int i = 0; i < 16; ++i) {
            cb[wq4*2048 + i*64 + ll]        = po[0][i];
            cb[wq4*2048 + (16+i)*64 + ll]   = po[1][i];
        }
        cb[8192 + 0*256 + wq4*64 + ll] = ls0;
        cb[8192 + 1*256 + wq4*64 + ll] = ls1;
    }
    __syncthreads();
    if (kh == 0) {
        #pragma unroll
        for (int i = 0; i < 16; ++i) {
            po[0][i] += cb[wq4*2048 + i*64 + ll];
            po[1][i] += cb[wq4*2048 + (16+i)*64 + ll];
        }
        ls0 += cb[8192 + 0*256 + wq4*64 + ll];
        ls1 += cb[8192 + 1*256 + wq4*64 + ll];
    }
    __syncthreads();
    if (kh == 1) {
        #pragma unroll
        for (int i = 0; i < 16; ++i) {
            cb[wq4*2048 + i*64 + ll]        = po[2][i];
            cb[wq4*2048 + (16+i)*64 + ll]   = po[3][i];
        }
    }
    __syncthreads();
    if (kh == 0) {
        #pragma unroll
        for (int i = 0; i < 16; ++i) {
            po[2][i] += cb[wq4*2048 + i*64 + ll];
            po[3][i] += cb[wq4*2048 + (16+i)*64 + ll];
        }
    }
    __syncthreads();

    // ---- epilogue (waves 0-3): normalize + transpose via wave-local LDS ----
    if (kh == 0) {
        // cross-half (hi) completion of the row sums: pure add, deferred here
        float lst[2];
        lst[0] = ls0 + __shfl_xor(ls0, 32);
        lst[1] = ls1 + __shfl_xor(ls1, 32);
        u16* ow = &smem[wq4 * 2304];   // 32 rows x 72 u16 per wave (wave-local)
        #pragma unroll
        for (int qg = 0; qg < 2; ++qg) {
            float inv = 1.f / lst[qg];
            #pragma unroll
            for (int r = 0; r < 16; ++r) {
                int d0 = (r & 3) + 8 * (r >> 2) + 4 * hi;
                ow[q * 72 + d0]      = f2bf(po[qg*2 + 0][r] * inv);
                ow[q * 72 + 32 + d0] = f2bf(po[qg*2 + 1][r] * inv);
            }
            int row = ll >> 1, half = t & 1;
            const u16* orow = &ow[row * 72 + half * 32];
            u16* gp = &CTX[(size_t)(b*S + qbase + qg*32 + row) * D + h*DH + half * 32];
            #pragma unroll
            for (int i = 0; i < 4; ++i)
                *(bf16x8*)(gp + i * 8) = *(const bf16x8*)(orow + i * 8);
        }
    }
}

extern "C" void kernel_launch(void* const* d_in, const int* in_sizes, int n_in,
                              void* d_out, int out_size, void* d_ws, size_t ws_size,
                              hipStream_t stream)
{
    const float* x    = (const float*)d_in[0];
    const float* cosT = (const float*)d_in[1];
    const float* sinT = (const float*)d_in[2];
    const float* wq   = (const float*)d_in[3];
    const float* wk   = (const float*)d_in[4];
    const float* wv   = (const float*)d_in[5];
    const float* wo   = (const float*)d_in[6];
    float* out = (float*)d_out;

    const size_t MD = (size_t)M_TOT * D;
    const size_t WD = (size_t)D * D;

    u16* xb   = (u16*)d_ws;
    u16* Qb   = xb + MD;
    u16* Kb   = Qb + MD;
    u16* Vtb  = Kb + MD;
    u16* CTXb = Vtb + MD;
    u16* wqb  = CTXb + MD;
    u16* wkb  = wqb + WD;
    u16* wvb  = wkb + WD;
    u16* wob  = wvb + WD;

    // 1. fused bf16 casts (x + 4 weights in one launch)
    cvt_all_kernel<<<(int)((MD + 4*WD) / 8 / 256), 256, 0, stream>>>(
        x, wq, wk, wv, wo, xb, wqb, wkb, wvb, wob);

    // 2. fused QKV projections (z=0: Q rope+scale, z=1: K rope, z=2: V -> Vt transposed)
    gemm_mfma<1, 1><<<dim3(M_TOT / 128, D / 128, 3), 256, 0, stream>>>(
        xb, wqb, wkb, wvb, Qb, Kb, Vtb, cosT, sinT);

    // 3. attention (8-wave key-split blocks, VALU lsum)
    attn_mfma<<<dim3(M_TOT / QBLK * H), 512, 0, stream>>>(Qb, Kb, Vtb, CTXb);

    // 4. output projection (fp32 out)
    gemm_mfma<0, 0><<<dim3(M_TOT / 128, D / 128, 1), 256, 0, stream>>>(
        CTXb, wob, nullptr, nullptr, out, nullptr, nullptr, nullptr, nullptr);
}